// Round 1
// 2687.683 us; speedup vs baseline: 1.3579x; 1.3579x over previous
//
#include <hip/hip_runtime.h>

// NeuralCDE RK4 — R6: phase-1 (z @ W1 + tanh) moved from fp32 VALU to the same
// 3-way-split bf16 MFMA scheme that phase-2 already uses (verified numerics).
// Phase-1 is computed TRANSPOSED (h^T = W1^T . z^T, M=mid, N=batch) so:
//   - B-fragment of z^T is a b128 row read of the z-split arrays (same pattern
//     as phase-2's verified A-read),
//   - D rows (q*4+r) are consecutive mids -> split-h store is one ds_write_b64
//     per (tile,split), conflict-free,
//   - phase-2's A-read layout sH*[batch][mid] is produced directly.
// z bf16 splits are generated in the contraction phase (2 values/thread).
// sG re-laid out as [b][i*33+o], batch stride 199 (odd): contraction reads
// 2 lanes/bank (free), stores <=3-way (was 4-way both directions).
// MFMA conventions = HW-verified m89/m120 mappings:
//   A[m=lane&15][k=quad*8+j], B[k=quad*8+j][n=lane&15], D[row=quad*4+r][col=lane&15]

typedef short short8  __attribute__((ext_vector_type(8)));
typedef short short4v __attribute__((ext_vector_type(4)));
typedef float floatx4 __attribute__((ext_vector_type(4)));

constexpr int B_TOT  = 8192;
constexpr int L      = 256;
constexpr int CIN    = 6;
constexpr int H      = 32;
constexpr int MID    = 128;
constexpr int NSTEPS = L - 1;   // 255
constexpr int NB     = 16;      // batches per WG (one 16-row M tile)
constexpr int WG     = 256;     // 4 waves
// grid = B_TOT/NB = 512 -> 2 blocks/CU

constexpr int HP  = 144;   // h split row stride (shorts): 288 B/row, 16B-aligned
constexpr int ZSP = 48;    // z split row stride (shorts): 96 B/row, 16B-aligned
constexpr int GIS = 33;    // sG i-stride (floats)
constexpr int GBS = 199;   // sG batch-stride (floats), odd -> conflict-light
constexpr int ZP  = 33;    // fp32 z rows (odd -> conflict-free scalar)

__device__ __forceinline__ short f2bf(float x) {     // RNE fp32 -> bf16 bits
    unsigned u = __builtin_bit_cast(unsigned, x);
    unsigned r = (u + 0x7FFFu + ((u >> 16) & 1u)) >> 16;
    return (short)r;
}
__device__ __forceinline__ float bf2f(short b) {
    unsigned u = ((unsigned)(unsigned short)b) << 16;
    return __builtin_bit_cast(float, u);
}

__global__ __launch_bounds__(WG, 2)
void cde_hybrid_kernel(const float* __restrict__ times,
                       const float* __restrict__ coeff_b,
                       const float* __restrict__ coeff_c,
                       const float* __restrict__ coeff_d,
                       const float* __restrict__ W1g,
                       const float* __restrict__ b1g,
                       const float* __restrict__ W2g,
                       const float* __restrict__ b2g,
                       const float* __restrict__ Wlg,
                       const float* __restrict__ blg,
                       float* __restrict__ out)
{
    __shared__ __align__(16) short sHh[NB][HP], sHm[NB][HP], sHl[NB][HP]; // 13.5 KB
    __shared__ float sGf[NB * GBS + 4];                                   // 12.75 KB
    __shared__ __align__(16) short sZh[NB][ZSP], sZm[NB][ZSP], sZl[NB][ZSP]; // 4.5 KB
    __shared__ float sZb[NB][ZP], sZa[NB][ZP];                            // 4.2 KB
    __shared__ float sDx[3][NB][8];                                       // 1.5 KB

    const int tid  = threadIdx.x;
    const int lane = tid & 63;
    const int wave = tid >> 6;      // 0..3
    const int l15  = lane & 15;
    const int q    = lane >> 4;     // 0..3
    const int b0   = blockIdx.x * NB;

    // ---- one-time: W2 fragments -> registers (bf16 hi/mid/lo), phase-2 B ----
    // wave covers N-tiles {3*wave .. 3*wave+2}; K covered by ks=0..3.
    short8 w2h[3][4], w2m[3][4], w2l[3][4];
    float  b2v[3];
    int    gofs[3];                 // precomputed (n%6)*GIS + n/6 for sG stores
    #pragma unroll
    for (int f = 0; f < 3; ++f) {
        const int n = (wave * 3 + f) * 16 + l15;
        b2v[f]  = b2g[n];
        gofs[f] = (n % 6) * GIS + (n / 6);
        #pragma unroll
        for (int ks = 0; ks < 4; ++ks) {
            #pragma unroll
            for (int j = 0; j < 8; ++j) {
                const float w = W2g[(ks * 32 + q * 8 + j) * (H * CIN) + n];
                const short hh = f2bf(w);        const float r1 = w - bf2f(hh);
                const short mm = f2bf(r1);       const float r2 = r1 - bf2f(mm);
                w2h[f][ks][j] = hh; w2m[f][ks][j] = mm; w2l[f][ks][j] = f2bf(r2);
            }
        }
    }

    // ---- one-time: W1^T fragments -> registers (bf16 hi/mid/lo), phase-1 A ----
    // wave covers mid-tiles {2*wave, 2*wave+1}; K=H=32 in one MFMA pass.
    // A[m=l15][k=q*8+j] = W1^T[mt*16+l15][k] = W1[k][mt*16+l15]
    short8 w1h[2], w1m[2], w1l[2];
    float  b1v[2][4];
    #pragma unroll
    for (int f1 = 0; f1 < 2; ++f1) {
        const int mt = wave * 2 + f1;
        #pragma unroll
        for (int j = 0; j < 8; ++j) {
            const float w = W1g[(q * 8 + j) * MID + mt * 16 + l15];
            const short hh = f2bf(w);        const float r1 = w - bf2f(hh);
            const short mm = f2bf(r1);       const float r2 = r1 - bf2f(mm);
            w1h[f1][j] = hh; w1m[f1][j] = mm; w1l[f1][j] = f2bf(r2);
        }
        #pragma unroll
        for (int r = 0; r < 4; ++r)
            b1v[f1][r] = b1g[mt * 16 + q * 4 + r];   // D row = mid = mt*16+q*4+r
    }

    // ---- one-time init: z state (fp32 + bf16 splits) to zero ----
    for (int i = tid; i < NB * ZP; i += WG) {
        (&sZb[0][0])[i] = 0.f; (&sZa[0][0])[i] = 0.f;
    }
    for (int i = tid; i < NB * ZSP; i += WG) {
        (&sZh[0][0])[i] = 0; (&sZm[0][0])[i] = 0; (&sZl[0][0])[i] = 0;
    }
    __syncthreads();

    for (int t = 0; t < NSTEPS; ++t) {
        const float dt = times[t + 1] - times[t];
        if (tid < NB * CIN) {
            const int bb = tid / CIN, ii = tid - bb * CIN;
            const size_t off = ((size_t)(b0 + bb) * NSTEPS + t) * CIN + ii;
            const float vb = coeff_b[off], vc = coeff_c[off], vd = coeff_d[off];
            const float f1 = 0.5f * dt;
            sDx[0][bb][ii] = vb;                              // dX(0)
            sDx[1][bb][ii] = vb + vc * f1 + vd * f1 * f1;     // dX(dt/2)
            sDx[2][bb][ii] = vb + vc * dt + vd * dt * dt;     // dX(dt)
        }
        __syncthreads();

        #pragma unroll 1
        for (int s = 0; s < 4; ++s) {
            // ---------- phase 1 (MFMA): h^T = tanh(W1^T @ z^T + b1) ----------
            // B-frag: B[k=q*8+j][n=l15] = z[l15][q*8+j]  (b128 row read)
            const short8 zh = *(const short8*)&sZh[l15][q * 8];
            const short8 zm = *(const short8*)&sZm[l15][q * 8];
            const short8 zl = *(const short8*)&sZl[l15][q * 8];
            floatx4 ht[2];
            #pragma unroll
            for (int f1 = 0; f1 < 2; ++f1) ht[f1] = floatx4{0.f, 0.f, 0.f, 0.f};
            #pragma unroll
            for (int f1 = 0; f1 < 2; ++f1) {
                ht[f1] = __builtin_amdgcn_mfma_f32_16x16x32_bf16(w1h[f1], zh, ht[f1], 0, 0, 0);
                ht[f1] = __builtin_amdgcn_mfma_f32_16x16x32_bf16(w1h[f1], zm, ht[f1], 0, 0, 0);
                ht[f1] = __builtin_amdgcn_mfma_f32_16x16x32_bf16(w1m[f1], zh, ht[f1], 0, 0, 0);
                ht[f1] = __builtin_amdgcn_mfma_f32_16x16x32_bf16(w1h[f1], zl, ht[f1], 0, 0, 0);
                ht[f1] = __builtin_amdgcn_mfma_f32_16x16x32_bf16(w1m[f1], zm, ht[f1], 0, 0, 0);
                ht[f1] = __builtin_amdgcn_mfma_f32_16x16x32_bf16(w1l[f1], zh, ht[f1], 0, 0, 0);
            }
            // D[row=q*4+r][col=l15] = h^T[mid=mt*16+q*4+r][batch=l15]
            // -> bias, tanh, 3-way split, store 4 consecutive mids as b64
            #pragma unroll
            for (int f1 = 0; f1 < 2; ++f1) {
                const int mt = wave * 2 + f1;
                short4v vh, vm, vl;
                #pragma unroll
                for (int r = 0; r < 4; ++r) {
                    const float pre = ht[f1][r] + b1v[f1][r];
                    const float e = __expf(2.f * pre);        // tanh
                    const float h = 1.f - 2.f / (e + 1.f);
                    const short hh = f2bf(h);   const float r1 = h - bf2f(hh);
                    const short hm = f2bf(r1);  const float r2 = r1 - bf2f(hm);
                    vh[r] = hh; vm[r] = hm; vl[r] = f2bf(r2);
                }
                *(short4v*)&sHh[l15][mt * 16 + q * 4] = vh;
                *(short4v*)&sHm[l15][mt * 16 + q * 4] = vm;
                *(short4v*)&sHl[l15][mt * 16 + q * 4] = vl;
            }
            __syncthreads();

            // ---------- phase 2 (MFMA): G = h @ W2 + b2, K=128 ----------
            floatx4 g[3];
            #pragma unroll
            for (int f = 0; f < 3; ++f) g[f] = floatx4{0.f, 0.f, 0.f, 0.f};
            #pragma unroll
            for (int ks = 0; ks < 4; ++ks) {
                const short8 ah = *(const short8*)&sHh[l15][ks * 32 + q * 8];
                const short8 am = *(const short8*)&sHm[l15][ks * 32 + q * 8];
                const short8 al = *(const short8*)&sHl[l15][ks * 32 + q * 8];
                #pragma unroll
                for (int f = 0; f < 3; ++f) {
                    g[f] = __builtin_amdgcn_mfma_f32_16x16x32_bf16(ah, w2h[f][ks], g[f], 0, 0, 0);
                    g[f] = __builtin_amdgcn_mfma_f32_16x16x32_bf16(ah, w2m[f][ks], g[f], 0, 0, 0);
                    g[f] = __builtin_amdgcn_mfma_f32_16x16x32_bf16(am, w2h[f][ks], g[f], 0, 0, 0);
                    g[f] = __builtin_amdgcn_mfma_f32_16x16x32_bf16(ah, w2l[f][ks], g[f], 0, 0, 0);
                    g[f] = __builtin_amdgcn_mfma_f32_16x16x32_bf16(am, w2m[f][ks], g[f], 0, 0, 0);
                    g[f] = __builtin_amdgcn_mfma_f32_16x16x32_bf16(al, w2h[f][ks], g[f], 0, 0, 0);
                }
            }
            // store in [b][i*GIS+o] layout: addr = batch*GBS + (n%6)*GIS + n/6
            #pragma unroll
            for (int f = 0; f < 3; ++f) {
                #pragma unroll
                for (int r = 0; r < 4; ++r)
                    sGf[(q * 4 + r) * GBS + gofs[f]] = g[f][r] + b2v[f];
            }
            __syncthreads();

            // ---------- contraction k = G . dx, RK4 update, z-split ----------
            const int dsel = (s == 0) ? 0 : ((s == 3) ? 2 : 1);
            const float ws = (s == 0 || s == 3) ? dt * (1.f / 6.f) : dt * (1.f / 3.f);
            #pragma unroll
            for (int jj = 0; jj < 2; ++jj) {
                const int pp = tid + 256 * jj;
                const int b = pp >> 5, o = pp & 31;     // 16 batches x 32 outputs
                float k = 0.f;
                #pragma unroll
                for (int i = 0; i < 6; ++i)
                    k += sGf[b * GBS + i * GIS + o] * sDx[dsel][b][i];
                const float za = sZa[b][o] + ws * k;
                sZa[b][o] = za;
                float zc;
                if (s < 3) {
                    zc = sZb[b][o] + ((s == 2) ? dt : 0.5f * dt) * k;
                } else {
                    sZb[b][o] = za;
                    zc = za;
                }
                // 3-way bf16 split of the next-stage z (phase-1 B operand)
                const short zh0 = f2bf(zc);  const float zr1 = zc - bf2f(zh0);
                const short zm0 = f2bf(zr1); const float zr2 = zr1 - bf2f(zm0);
                sZh[b][o] = zh0; sZm[b][o] = zm0; sZl[b][o] = f2bf(zr2);
            }
            __syncthreads();
        }
    }

    // ---------- readout: out = zT @ Wl + bl ----------
    if (tid < NB * CIN) {
        const int bb = tid / CIN, c = tid - bb * CIN;
        float acc = blg[c];
        #pragma unroll
        for (int o = 0; o < H; ++o) acc += sZb[bb][o] * Wlg[o * CIN + c];
        out[(size_t)(b0 + bb) * CIN + c] = acc;
    }
}

extern "C" void kernel_launch(void* const* d_in, const int* in_sizes, int n_in,
                              void* d_out, int out_size, void* d_ws, size_t ws_size,
                              hipStream_t stream) {
    const float* times = (const float*)d_in[0];
    // d_in[1] = coeff_a: unused by the reference vector field
    const float* cb = (const float*)d_in[2];
    const float* cc = (const float*)d_in[3];
    const float* cd = (const float*)d_in[4];
    const float* W1 = (const float*)d_in[5];
    const float* b1 = (const float*)d_in[6];
    const float* W2 = (const float*)d_in[7];
    const float* b2 = (const float*)d_in[8];
    const float* Wl = (const float*)d_in[9];
    const float* bl = (const float*)d_in[10];
    float* out = (float*)d_out;

    hipLaunchKernelGGL(cde_hybrid_kernel, dim3(B_TOT / NB), dim3(WG), 0, stream,
                       times, cb, cc, cd, W1, b1, W2, b2, Wl, bl, out);
}

// Round 2
// 2552.824 us; speedup vs baseline: 1.4297x; 1.0528x over previous
//
#include <hip/hip_runtime.h>

// NeuralCDE RK4 — R7: bank-conflict fix on R6 (pure LDS stride retune, zero
// arithmetic change). R6 tripled SQ_LDS_BANK_CONFLICT (1.0e8 -> 3.35e8 = 20%
// of all CU cycles) because:
//   - sH* row stride 144 shorts = 72 dwords === 8 mod 32 -> phase-2 A-reads
//     (b128) collapse to 4 bank-slots per 8-lane group; h-stores 4-way.
//   - sZ* row stride 48 shorts = 24 dwords === 24 mod 32 -> z-reads 4-way.
// Fix: HP 144->152 (76 dwords === 12 mod 32: l15*12 enumerates all 8 4-bank
// slots per 8-lane group -> b128 reads conflict-free, b64 stores 2-way=free);
// ZSP 48->72 (36 dwords === 4 mod 32: perfect spread). Rows stay 16B-aligned.
// MFMA conventions = HW-verified m89/m120 mappings:
//   A[m=lane&15][k=quad*8+j], B[k=quad*8+j][n=lane&15], D[row=quad*4+r][col=lane&15]

typedef short short8  __attribute__((ext_vector_type(8)));
typedef short short4v __attribute__((ext_vector_type(4)));
typedef float floatx4 __attribute__((ext_vector_type(4)));

constexpr int B_TOT  = 8192;
constexpr int L      = 256;
constexpr int CIN    = 6;
constexpr int H      = 32;
constexpr int MID    = 128;
constexpr int NSTEPS = L - 1;   // 255
constexpr int NB     = 16;      // batches per WG (one 16-row M tile)
constexpr int WG     = 256;     // 4 waves
// grid = B_TOT/NB = 512 -> 2 blocks/CU

constexpr int HP  = 152;   // h split row stride (shorts): 304 B = 76 dw === 12 mod 32
                           //  -> A-read b128: 12*l15 mod 32 = {0,12,24,4,16,28,8,20}
                           //     per 8-lane group = all 8 slots once (conflict-free)
constexpr int ZSP = 72;    // z split row stride (shorts): 144 B = 36 dw === 4 mod 32
                           //  -> z-read b128 perfect 8-slot spread
constexpr int GIS = 33;    // sG i-stride (floats)
constexpr int GBS = 199;   // sG batch-stride (floats): read bank = 7b+i+o -> 2-way
constexpr int ZP  = 33;    // fp32 z rows (odd -> conflict-free scalar)

__device__ __forceinline__ short f2bf(float x) {     // RNE fp32 -> bf16 bits
    unsigned u = __builtin_bit_cast(unsigned, x);
    unsigned r = (u + 0x7FFFu + ((u >> 16) & 1u)) >> 16;
    return (short)r;
}
__device__ __forceinline__ float bf2f(short b) {
    unsigned u = ((unsigned)(unsigned short)b) << 16;
    return __builtin_bit_cast(float, u);
}

__global__ __launch_bounds__(WG, 2)
void cde_hybrid_kernel(const float* __restrict__ times,
                       const float* __restrict__ coeff_b,
                       const float* __restrict__ coeff_c,
                       const float* __restrict__ coeff_d,
                       const float* __restrict__ W1g,
                       const float* __restrict__ b1g,
                       const float* __restrict__ W2g,
                       const float* __restrict__ b2g,
                       const float* __restrict__ Wlg,
                       const float* __restrict__ blg,
                       float* __restrict__ out)
{
    __shared__ __align__(16) short sHh[NB][HP], sHm[NB][HP], sHl[NB][HP]; // 14.25 KB
    __shared__ float sGf[NB * GBS + 4];                                   // 12.75 KB
    __shared__ __align__(16) short sZh[NB][ZSP], sZm[NB][ZSP], sZl[NB][ZSP]; // 6.75 KB
    __shared__ float sZb[NB][ZP], sZa[NB][ZP];                            // 4.2 KB
    __shared__ float sDx[3][NB][8];                                       // 1.5 KB

    const int tid  = threadIdx.x;
    const int lane = tid & 63;
    const int wave = tid >> 6;      // 0..3
    const int l15  = lane & 15;
    const int q    = lane >> 4;     // 0..3
    const int b0   = blockIdx.x * NB;

    // ---- one-time: W2 fragments -> registers (bf16 hi/mid/lo), phase-2 B ----
    // wave covers N-tiles {3*wave .. 3*wave+2}; K covered by ks=0..3.
    short8 w2h[3][4], w2m[3][4], w2l[3][4];
    float  b2v[3];
    int    gofs[3];                 // precomputed (n%6)*GIS + n/6 for sG stores
    #pragma unroll
    for (int f = 0; f < 3; ++f) {
        const int n = (wave * 3 + f) * 16 + l15;
        b2v[f]  = b2g[n];
        gofs[f] = (n % 6) * GIS + (n / 6);
        #pragma unroll
        for (int ks = 0; ks < 4; ++ks) {
            #pragma unroll
            for (int j = 0; j < 8; ++j) {
                const float w = W2g[(ks * 32 + q * 8 + j) * (H * CIN) + n];
                const short hh = f2bf(w);        const float r1 = w - bf2f(hh);
                const short mm = f2bf(r1);       const float r2 = r1 - bf2f(mm);
                w2h[f][ks][j] = hh; w2m[f][ks][j] = mm; w2l[f][ks][j] = f2bf(r2);
            }
        }
    }

    // ---- one-time: W1^T fragments -> registers (bf16 hi/mid/lo), phase-1 A ----
    // wave covers mid-tiles {2*wave, 2*wave+1}; K=H=32 in one MFMA pass.
    // A[m=l15][k=q*8+j] = W1^T[mt*16+l15][k] = W1[k][mt*16+l15]
    short8 w1h[2], w1m[2], w1l[2];
    float  b1v[2][4];
    #pragma unroll
    for (int f1 = 0; f1 < 2; ++f1) {
        const int mt = wave * 2 + f1;
        #pragma unroll
        for (int j = 0; j < 8; ++j) {
            const float w = W1g[(q * 8 + j) * MID + mt * 16 + l15];
            const short hh = f2bf(w);        const float r1 = w - bf2f(hh);
            const short mm = f2bf(r1);       const float r2 = r1 - bf2f(mm);
            w1h[f1][j] = hh; w1m[f1][j] = mm; w1l[f1][j] = f2bf(r2);
        }
        #pragma unroll
        for (int r = 0; r < 4; ++r)
            b1v[f1][r] = b1g[mt * 16 + q * 4 + r];   // D row = mid = mt*16+q*4+r
    }

    // ---- one-time init: z state (fp32 + bf16 splits) to zero ----
    for (int i = tid; i < NB * ZP; i += WG) {
        (&sZb[0][0])[i] = 0.f; (&sZa[0][0])[i] = 0.f;
    }
    for (int i = tid; i < NB * ZSP; i += WG) {
        (&sZh[0][0])[i] = 0; (&sZm[0][0])[i] = 0; (&sZl[0][0])[i] = 0;
    }
    __syncthreads();

    for (int t = 0; t < NSTEPS; ++t) {
        const float dt = times[t + 1] - times[t];
        if (tid < NB * CIN) {
            const int bb = tid / CIN, ii = tid - bb * CIN;
            const size_t off = ((size_t)(b0 + bb) * NSTEPS + t) * CIN + ii;
            const float vb = coeff_b[off], vc = coeff_c[off], vd = coeff_d[off];
            const float f1 = 0.5f * dt;
            sDx[0][bb][ii] = vb;                              // dX(0)
            sDx[1][bb][ii] = vb + vc * f1 + vd * f1 * f1;     // dX(dt/2)
            sDx[2][bb][ii] = vb + vc * dt + vd * dt * dt;     // dX(dt)
        }
        __syncthreads();

        #pragma unroll 1
        for (int s = 0; s < 4; ++s) {
            // ---------- phase 1 (MFMA): h^T = tanh(W1^T @ z^T + b1) ----------
            // B-frag: B[k=q*8+j][n=l15] = z[l15][q*8+j]  (b128 row read)
            const short8 zh = *(const short8*)&sZh[l15][q * 8];
            const short8 zm = *(const short8*)&sZm[l15][q * 8];
            const short8 zl = *(const short8*)&sZl[l15][q * 8];
            floatx4 ht[2];
            #pragma unroll
            for (int f1 = 0; f1 < 2; ++f1) ht[f1] = floatx4{0.f, 0.f, 0.f, 0.f};
            #pragma unroll
            for (int f1 = 0; f1 < 2; ++f1) {
                ht[f1] = __builtin_amdgcn_mfma_f32_16x16x32_bf16(w1h[f1], zh, ht[f1], 0, 0, 0);
                ht[f1] = __builtin_amdgcn_mfma_f32_16x16x32_bf16(w1h[f1], zm, ht[f1], 0, 0, 0);
                ht[f1] = __builtin_amdgcn_mfma_f32_16x16x32_bf16(w1m[f1], zh, ht[f1], 0, 0, 0);
                ht[f1] = __builtin_amdgcn_mfma_f32_16x16x32_bf16(w1h[f1], zl, ht[f1], 0, 0, 0);
                ht[f1] = __builtin_amdgcn_mfma_f32_16x16x32_bf16(w1m[f1], zm, ht[f1], 0, 0, 0);
                ht[f1] = __builtin_amdgcn_mfma_f32_16x16x32_bf16(w1l[f1], zh, ht[f1], 0, 0, 0);
            }
            // D[row=q*4+r][col=l15] = h^T[mid=mt*16+q*4+r][batch=l15]
            // -> bias, tanh, 3-way split, store 4 consecutive mids as b64
            #pragma unroll
            for (int f1 = 0; f1 < 2; ++f1) {
                const int mt = wave * 2 + f1;
                short4v vh, vm, vl;
                #pragma unroll
                for (int r = 0; r < 4; ++r) {
                    const float pre = ht[f1][r] + b1v[f1][r];
                    const float e = __expf(2.f * pre);        // tanh
                    const float h = 1.f - 2.f / (e + 1.f);
                    const short hh = f2bf(h);   const float r1 = h - bf2f(hh);
                    const short hm = f2bf(r1);  const float r2 = r1 - bf2f(hm);
                    vh[r] = hh; vm[r] = hm; vl[r] = f2bf(r2);
                }
                *(short4v*)&sHh[l15][mt * 16 + q * 4] = vh;
                *(short4v*)&sHm[l15][mt * 16 + q * 4] = vm;
                *(short4v*)&sHl[l15][mt * 16 + q * 4] = vl;
            }
            __syncthreads();

            // ---------- phase 2 (MFMA): G = h @ W2 + b2, K=128 ----------
            floatx4 g[3];
            #pragma unroll
            for (int f = 0; f < 3; ++f) g[f] = floatx4{0.f, 0.f, 0.f, 0.f};
            #pragma unroll
            for (int ks = 0; ks < 4; ++ks) {
                const short8 ah = *(const short8*)&sHh[l15][ks * 32 + q * 8];
                const short8 am = *(const short8*)&sHm[l15][ks * 32 + q * 8];
                const short8 al = *(const short8*)&sHl[l15][ks * 32 + q * 8];
                #pragma unroll
                for (int f = 0; f < 3; ++f) {
                    g[f] = __builtin_amdgcn_mfma_f32_16x16x32_bf16(ah, w2h[f][ks], g[f], 0, 0, 0);
                    g[f] = __builtin_amdgcn_mfma_f32_16x16x32_bf16(ah, w2m[f][ks], g[f], 0, 0, 0);
                    g[f] = __builtin_amdgcn_mfma_f32_16x16x32_bf16(am, w2h[f][ks], g[f], 0, 0, 0);
                    g[f] = __builtin_amdgcn_mfma_f32_16x16x32_bf16(ah, w2l[f][ks], g[f], 0, 0, 0);
                    g[f] = __builtin_amdgcn_mfma_f32_16x16x32_bf16(am, w2m[f][ks], g[f], 0, 0, 0);
                    g[f] = __builtin_amdgcn_mfma_f32_16x16x32_bf16(al, w2h[f][ks], g[f], 0, 0, 0);
                }
            }
            // store in [b][i*GIS+o] layout: addr = batch*GBS + (n%6)*GIS + n/6
            #pragma unroll
            for (int f = 0; f < 3; ++f) {
                #pragma unroll
                for (int r = 0; r < 4; ++r)
                    sGf[(q * 4 + r) * GBS + gofs[f]] = g[f][r] + b2v[f];
            }
            __syncthreads();

            // ---------- contraction k = G . dx, RK4 update, z-split ----------
            const int dsel = (s == 0) ? 0 : ((s == 3) ? 2 : 1);
            const float ws = (s == 0 || s == 3) ? dt * (1.f / 6.f) : dt * (1.f / 3.f);
            #pragma unroll
            for (int jj = 0; jj < 2; ++jj) {
                const int pp = tid + 256 * jj;
                const int b = pp >> 5, o = pp & 31;     // 16 batches x 32 outputs
                float k = 0.f;
                #pragma unroll
                for (int i = 0; i < 6; ++i)
                    k += sGf[b * GBS + i * GIS + o] * sDx[dsel][b][i];
                const float za = sZa[b][o] + ws * k;
                sZa[b][o] = za;
                float zc;
                if (s < 3) {
                    zc = sZb[b][o] + ((s == 2) ? dt : 0.5f * dt) * k;
                } else {
                    sZb[b][o] = za;
                    zc = za;
                }
                // 3-way bf16 split of the next-stage z (phase-1 B operand)
                const short zh0 = f2bf(zc);  const float zr1 = zc - bf2f(zh0);
                const short zm0 = f2bf(zr1); const float zr2 = zr1 - bf2f(zm0);
                sZh[b][o] = zh0; sZm[b][o] = zm0; sZl[b][o] = f2bf(zr2);
            }
            __syncthreads();
        }
    }

    // ---------- readout: out = zT @ Wl + bl ----------
    if (tid < NB * CIN) {
        const int bb = tid / CIN, c = tid - bb * CIN;
        float acc = blg[c];
        #pragma unroll
        for (int o = 0; o < H; ++o) acc += sZb[bb][o] * Wlg[o * CIN + c];
        out[(size_t)(b0 + bb) * CIN + c] = acc;
    }
}

extern "C" void kernel_launch(void* const* d_in, const int* in_sizes, int n_in,
                              void* d_out, int out_size, void* d_ws, size_t ws_size,
                              hipStream_t stream) {
    const float* times = (const float*)d_in[0];
    // d_in[1] = coeff_a: unused by the reference vector field
    const float* cb = (const float*)d_in[2];
    const float* cc = (const float*)d_in[3];
    const float* cd = (const float*)d_in[4];
    const float* W1 = (const float*)d_in[5];
    const float* b1 = (const float*)d_in[6];
    const float* W2 = (const float*)d_in[7];
    const float* b2 = (const float*)d_in[8];
    const float* Wl = (const float*)d_in[9];
    const float* bl = (const float*)d_in[10];
    float* out = (float*)d_out;

    hipLaunchKernelGGL(cde_hybrid_kernel, dim3(B_TOT / NB), dim3(WG), 0, stream,
                       times, cb, cc, cd, W1, b1, W2, b2, Wl, bl, out);
}